// Round 28
// baseline (74.213 us; speedup 1.0000x reference)
//
#include <hip/hip_runtime.h>
#include <hip/hip_bf16.h>

#define TT 2048
#define CC 1024
#define DD 128
#define BB 8
#define BK 32
#define NSTEP (CC / BK)   // 32 K-steps

typedef __attribute__((ext_vector_type(8))) short bf16x8;
typedef __attribute__((ext_vector_type(4))) float f32x4;
typedef __attribute__((ext_vector_type(16))) float f32x16;
typedef __attribute__((ext_vector_type(4))) short short4v;

// Native bf16 convert (RNE) — compiles to v_cvt_pk_bf16_f32 pairs.
__device__ inline short f2bf(float f) {
    __bf16 h = (__bf16)f;
    union { __bf16 b; short s; } u; u.b = h;
    return u.s;
}

__device__ inline unsigned pack2(float lo, float hi) {  // two f32 -> packed bf16x2 word
    return (unsigned)(unsigned short)f2bf(lo) | ((unsigned)(unsigned short)f2bf(hi) << 16);
}

// async global->LDS, 16B per lane (guide §5 / Common-mistake #1)
#define GLOAD16(gp, lp) __builtin_amdgcn_global_load_lds(                       \
    (const __attribute__((address_space(1))) unsigned int*)(const void*)(gp),   \
    (__attribute__((address_space(3))) unsigned int*)(void*)(lp), 16, 0, 0)

// ---------------- Kernel 1: pack Wq|Wk|Wv -> bf16 Wall[384][1024] ----------------
__global__ __launch_bounds__(256) void prep_w(const float* __restrict__ Wq,
                                              const float* __restrict__ Wk,
                                              const float* __restrict__ Wv,
                                              short* __restrict__ Wall) {
    int row = blockIdx.x;  // 0..383
    const float* src = row < 128 ? Wq + (size_t)row * CC
                     : row < 256 ? Wk + (size_t)(row - 128) * CC
                                 : Wv + (size_t)(row - 256) * CC;
    short* dst = Wall + (size_t)row * CC;
    int j = threadIdx.x * 4;
    float4 f = *(const float4*)(src + j);
    short4v s = { f2bf(f.x), f2bf(f.y), f2bf(f.z), f2bf(f.w) };
    *(short4v*)(dst + j) = s;
}

// ---------------- Kernel 2: fused QKV GEMM (r17/r21/r24/r25/r27-verified best) ----
// Tile 64(M)x128(N), BK=32, 4 waves (2x2), grid (256,3): col-tile -> Q/K/Vs.
// A staged fp32 with (row&7)<<4 XOR-swizzle (pre-swizzled global src, full-offset-
// XOR read). B staged bf16 linear, 4 lanes per row (64B coalesced segments).
__global__ __launch_bounds__(256) void qkv_fused(const float* __restrict__ X,
                                                 const short* __restrict__ Wall,
                                                 short* __restrict__ Q,
                                                 short* __restrict__ K,
                                                 short* __restrict__ Vs) {
    __shared__ char lds[2 * 16384];   // per buf: A fp32 8KB | B bf16 8KB
    int tid = threadIdx.x, lane = tid & 63, wid = tid >> 6;
    int wm = wid >> 1, wn = wid & 1;
    int lg = lane >> 4, lr = lane & 15;
    int m0 = blockIdx.x * 64;
    int n0 = blockIdx.y * 128;

    // A staging: 512 16B-chunks; thread stages chunks tid and tid+256 (rows +32)
    int rA = tid >> 3;                     // 0..31
    int cA = (tid & 7) * 16;               // byte col in 128B row
    int sA = cA ^ ((rA & 7) << 4);         // pre-swizzled source col
    const char* gA0 = (const char*)(X + (size_t)(m0 + rA) * CC) + sA;
    const char* gA1 = (const char*)(X + (size_t)(m0 + rA + 32) * CC) + sA;
    // B staging: 512 16B-chunks linear; rows n0..n0+127, 4 lanes per row (64B)
    int rB = tid >> 2, cB = (tid & 3) * 16;
    const char* gB0 = (const char*)(Wall + (size_t)(n0 + rB) * CC) + cB;
    const char* gB1 = (const char*)(Wall + (size_t)(n0 + rB + 64) * CC) + cB;

    f32x4 acc[2][4] = {};

#define STAGEF(t_, buf_) do {                                                   \
        char* b_ = lds + (buf_) * 16384;                                        \
        size_t ka_ = (size_t)(t_) * 128;   /* bytes into fp32 A row */          \
        size_t kb_ = (size_t)(t_) * 64;    /* bytes into bf16 B row */          \
        GLOAD16(gA0 + ka_, b_ + tid * 16);                                      \
        GLOAD16(gA1 + ka_, b_ + 4096 + tid * 16);                               \
        GLOAD16(gB0 + kb_, b_ + 8192 + tid * 16);                               \
        GLOAD16(gB1 + kb_, b_ + 12288 + tid * 16);                              \
    } while (0)

#define KSTEPF(buf_) do {                                                       \
        const char* b_ = lds + (buf_) * 16384;                                  \
        bf16x8 a_[2], bb_[4];                                                   \
        int swz_ = (lr & 7) << 4;                                               \
        _Pragma("unroll")                                                       \
        for (int mi = 0; mi < 2; ++mi) {                                        \
            const char* Ap_ = b_ + (wm * 32 + mi * 16 + lr) * 128;              \
            f32x4 lo_ = *(const f32x4*)(Ap_ + ((lg * 32) ^ swz_));              \
            f32x4 hi_ = *(const f32x4*)(Ap_ + ((lg * 32 + 16) ^ swz_));         \
            bf16x8 t_;                                                          \
            t_[0] = f2bf(lo_[0]); t_[1] = f2bf(lo_[1]);                         \
            t_[2] = f2bf(lo_[2]); t_[3] = f2bf(lo_[3]);                         \
            t_[4] = f2bf(hi_[0]); t_[5] = f2bf(hi_[1]);                         \
            t_[6] = f2bf(hi_[2]); t_[7] = f2bf(hi_[3]);                         \
            a_[mi] = t_;                                                        \
        }                                                                       \
        _Pragma("unroll")                                                       \
        for (int nj = 0; nj < 4; ++nj)                                          \
            bb_[nj] = *(const bf16x8*)(b_ + 8192 + (wn*64 + nj*16 + lr) * 64 + lg*16);\
        _Pragma("unroll")                                                       \
        for (int mi = 0; mi < 2; ++mi)                                          \
            _Pragma("unroll")                                                   \
            for (int nj = 0; nj < 4; ++nj)                                      \
                acc[mi][nj] = __builtin_amdgcn_mfma_f32_16x16x32_bf16(a_[mi], bb_[nj], acc[mi][nj], 0, 0, 0);\
    } while (0)

    STAGEF(0, 0);
#pragma unroll 2
    for (int t = 0; t < NSTEP; ++t) {
        __syncthreads();                   // staged tile t visible; reads of t-1 done
        if (t + 1 < NSTEP) STAGEF(t + 1, (t + 1) & 1);
        KSTEPF(t & 1);
    }
#undef STAGEF
#undef KSTEPF

    int bidx = m0 >> 11;
    int nt = blockIdx.y;
#pragma unroll
    for (int mi = 0; mi < 2; ++mi) {
        int row = m0 + wm * 32 + mi * 16 + lg * 4;
        int t = row - bidx * TT;
#pragma unroll
        for (int nj = 0; nj < 4; ++nj) {
            int col = wn * 64 + nj * 16 + lr;
            if (nt == 0) {
                short* dst = Q + ((size_t)bidx * TT + t) * DD + col;
#pragma unroll
                for (int r = 0; r < 4; ++r) dst[(size_t)r * DD] = f2bf(acc[mi][nj][r]);
            } else if (nt == 1) {
                short* dst = K + ((size_t)bidx * TT + t) * DD + col;
#pragma unroll
                for (int r = 0; r < 4; ++r) dst[(size_t)r * DD] = f2bf(acc[mi][nj][r]);
            } else {
                short4v v4;
#pragma unroll
                for (int r = 0; r < 4; ++r) v4[r] = f2bf(acc[mi][nj][r]);
                *(short4v*)(Vs + (size_t)bidx * TT * DD
                               + (size_t)(t >> 4) * 2048 + col * 16 + (t & 15)) = v4;
            }
        }
    }
}

// ---------------- PV macro: uses preloaded V fragments (r13-verified) ----------------
#define PV_CHUNK(WS, H, CB) do {                                                   \
    unsigned a0 = WS[4*(H)+0], a1 = WS[4*(H)+1];                                   \
    unsigned b0 = WS[4*(H)+2], b1 = WS[4*(H)+3];                                   \
    unsigned xa0 = (unsigned)__shfl_xor((int)a0, 32, 64);                          \
    unsigned xa1 = (unsigned)__shfl_xor((int)a1, 32, 64);                          \
    unsigned xb0 = (unsigned)__shfl_xor((int)b0, 32, 64);                          \
    unsigned xb1 = (unsigned)__shfl_xor((int)b1, 32, 64);                          \
    union { unsigned u[4]; bf16x8 v; } pu;                                         \
    pu.u[0] = lg2 ? xb0 : a0;                                                      \
    pu.u[1] = lg2 ? xb1 : a1;                                                      \
    pu.u[2] = lg2 ? b0  : xa0;                                                     \
    pu.u[3] = lg2 ? b1  : xa1;                                                     \
    _Pragma("unroll")                                                              \
    for (int dt = 0; dt < 4; ++dt)                                                 \
        acc[dt] = __builtin_amdgcn_mfma_f32_32x32x16_bf16(vf[CB][dt], pu.v, acc[dt], 0,0,0);\
} while (0)

// ---------------- Kernel 3: causal flash attention, 8 waves / q-tile --------------
// r25 structure; NEW: balanced two-generation block->qtile map. 512 blocks = 2
// sequential generations per CU. Old map paired CU j with (qt 63-j/8, qt 31-j/8):
// per-CU work varied ~47..17 key-units (1.7x) and kernel time = heaviest CU.
// New map: gen1 descends 63..32, gen2 ASCENDS 0..31 -> every CU pair sums to
// qt + (63-qt) ~= 33 units. Bijective: bid<256 -> qt 32..63, bid>=256 -> qt 0..31.
__global__ __launch_bounds__(512) void attn32(const short* __restrict__ Q,
                                              const short* __restrict__ K,
                                              const short* __restrict__ Vt,
                                              float* __restrict__ out) {
    __shared__ float slot[4][4][32][33];
    __shared__ float ml[4][2][32];

    int tid = threadIdx.x;
    int lane = tid & 63, w = tid >> 6;       // w = 0..7
    int q = lane & 31, lg2 = lane >> 5;
    int bid = blockIdx.x;
    int b = bid & 7;
    int qt = (bid < 256) ? 63 - (bid >> 3) : (bid - 256) >> 3;  // balanced pairing
    int r0 = qt * 32;
    int qq = r0 + q;

    const short* Qb = Q + (size_t)b * TT * DD;
    const short* Kb = K + (size_t)b * TT * DD;
    const short* Vb = Vt + (size_t)b * TT * DD;

    bf16x8 qf[8];
#pragma unroll
    for (int kc = 0; kc < 8; ++kc)
        qf[kc] = *(const bf16x8*)(Qb + (size_t)qq * DD + kc * 16 + lg2 * 8);

    f32x16 acc[4] = {};
    float mb = -INFINITY, l = 0.f;
    const float scale = 0.08838834764831845f;
    int kend = r0 + 32;

    for (int kt = w; kt * 64 < kend; kt += 8) {
        int kbase = kt * 64;
        f32x16 s0 = {}, s1 = {};
        const short* Kp0 = Kb + (size_t)(kbase + q) * DD + lg2 * 8;
        const short* Kp1 = Kp0 + (size_t)32 * DD;
#pragma unroll
        for (int kc = 0; kc < 8; ++kc) {
            bf16x8 k0 = *(const bf16x8*)(Kp0 + kc * 16);
            bf16x8 k1 = *(const bf16x8*)(Kp1 + kc * 16);
            s0 = __builtin_amdgcn_mfma_f32_32x32x16_bf16(k0, qf[kc], s0, 0, 0, 0);
            s1 = __builtin_amdgcn_mfma_f32_32x32x16_bf16(k1, qf[kc], s1, 0, 0, 0);
        }

        // V preload: addresses independent of softmax -> latency hides under it
        bf16x8 vf[4][4];
#pragma unroll
        for (int cb = 0; cb < 4; ++cb) {
            const short* Vp = Vb + ((size_t)((kbase >> 4) + cb) * 128 + q) * 16 + lg2 * 8;
#pragma unroll
            for (int dt = 0; dt < 4; ++dt)
                vf[cb][dt] = *(const bf16x8*)(Vp + dt * 512);
        }

        if (kbase + 63 > r0) {
#pragma unroll
            for (int r = 0; r < 16; ++r) {
                int kl = (r & 3) + 8 * (r >> 2) + 4 * lg2;
                s0[r] = (kbase + kl > qq) ? -INFINITY : s0[r] * scale;
                s1[r] = (kbase + 32 + kl > qq) ? -INFINITY : s1[r] * scale;
            }
        } else {
#pragma unroll
            for (int r = 0; r < 16; ++r) { s0[r] *= scale; s1[r] *= scale; }
        }

        float tmx[16];
#pragma unroll
        for (int r = 0; r < 16; ++r) tmx[r] = fmaxf(s0[r], s1[r]);
#pragma unroll
        for (int st = 8; st; st >>= 1)
#pragma unroll
            for (int r = 0; r < 8; ++r) if (r < st) tmx[r] = fmaxf(tmx[r], tmx[r + st]);
        float pm = fmaxf(tmx[0], __shfl_xor(tmx[0], 32, 64));

        if (__any(pm > mb + 8.f)) {
            float mn = fmaxf(mb, pm);
            float mc = (mn == -INFINITY) ? 0.f : mn;
            float sc = __expf(mb - mc);
            mb = mc; l *= sc;
#pragma unroll
            for (int dt = 0; dt < 4; ++dt)
#pragma unroll
                for (int r = 0; r < 16; ++r) acc[dt][r] *= sc;
        }

#pragma unroll
        for (int r = 0; r < 16; ++r) { s0[r] = __expf(s0[r] - mb); s1[r] = __expf(s1[r] - mb); }

        float ts[16];
#pragma unroll
        for (int r = 0; r < 16; ++r) ts[r] = s0[r] + s1[r];
#pragma unroll
        for (int st = 8; st; st >>= 1)
#pragma unroll
            for (int r = 0; r < 8; ++r) if (r < st) ts[r] += ts[r + st];
        l += ts[0] + __shfl_xor(ts[0], 32, 64);

        unsigned w0[8], w1[8];
#pragma unroll
        for (int k2 = 0; k2 < 8; ++k2) {
            w0[k2] = pack2(s0[2 * k2], s0[2 * k2 + 1]);
            w1[k2] = pack2(s1[2 * k2], s1[2 * k2 + 1]);
        }

        PV_CHUNK(w0, 0, 0);
        PV_CHUNK(w0, 1, 1);
        PV_CHUNK(w1, 0, 2);
        PV_CHUNK(w1, 1, 3);
    }

    // ---- level 1: waves 4-7 fold into waves 0-3 ----
    if (w >= 4) {
        int s = w - 4;
#pragma unroll
        for (int dt = 0; dt < 4; ++dt)
#pragma unroll
            for (int r = 0; r < 16; ++r)
                slot[s][dt][(r & 3) + 8 * (r >> 2) + 4 * lg2][q] = acc[dt][r];
        if (lg2 == 0) { ml[s][0][q] = mb; ml[s][1][q] = l; }
    }
    __syncthreads();
    if (w < 4) {
        int s = w;
        float m2 = ml[s][0][q], l2 = ml[s][1][q];
        float M = fmaxf(mb, m2);
        float Mc = (M == -INFINITY) ? 0.f : M;
        float e1 = __expf(mb - Mc), e2 = __expf(m2 - Mc);
        mb = Mc; l = l * e1 + l2 * e2;
#pragma unroll
        for (int dt = 0; dt < 4; ++dt)
#pragma unroll
            for (int r = 0; r < 16; ++r)
                acc[dt][r] = acc[dt][r] * e1 + slot[s][dt][(r & 3) + 8 * (r >> 2) + 4 * lg2][q] * e2;
    }
    __syncthreads();
    // ---- level 2: waves 2-3 fold into 0-1 ----
    if (w >= 2 && w < 4) {
        int s = w - 2;
#pragma unroll
        for (int dt = 0; dt < 4; ++dt)
#pragma unroll
            for (int r = 0; r < 16; ++r)
                slot[s][dt][(r & 3) + 8 * (r >> 2) + 4 * lg2][q] = acc[dt][r];
        if (lg2 == 0) { ml[s][0][q] = mb; ml[s][1][q] = l; }
    }
    __syncthreads();
    if (w < 2) {
        int s = w;
        float m2 = ml[s][0][q], l2 = ml[s][1][q];
        float M = fmaxf(mb, m2);
        float Mc = (M == -INFINITY) ? 0.f : M;
        float e1 = __expf(mb - Mc), e2 = __expf(m2 - Mc);
        mb = Mc; l = l * e1 + l2 * e2;
#pragma unroll
        for (int dt = 0; dt < 4; ++dt)
#pragma unroll
            for (int r = 0; r < 16; ++r)
                acc[dt][r] = acc[dt][r] * e1 + slot[s][dt][(r & 3) + 8 * (r >> 2) + 4 * lg2][q] * e2;
    }
    __syncthreads();
    if (w == 1) {
#pragma unroll
        for (int dt = 0; dt < 4; ++dt)
#pragma unroll
            for (int r = 0; r < 16; ++r)
                slot[0][dt][(r & 3) + 8 * (r >> 2) + 4 * lg2][q] = acc[dt][r];
        if (lg2 == 0) { ml[0][0][q] = mb; ml[0][1][q] = l; }
    }
    __syncthreads();
    if (w == 0) {
        float m2 = ml[0][0][q], l2 = ml[0][1][q];
        float M = fmaxf(mb, m2);
        float Mc = (M == -INFINITY) ? 0.f : M;
        float e1 = __expf(mb - Mc), e2 = __expf(m2 - Mc);
        l = l * e1 + l2 * e2;
        float inv = 1.f / l;
#pragma unroll
        for (int dt = 0; dt < 4; ++dt)
#pragma unroll
            for (int rq = 0; rq < 4; ++rq) {
                f32x4 o4;
#pragma unroll
                for (int j = 0; j < 4; ++j) {
                    int r = rq * 4 + j;
                    o4[j] = (acc[dt][r] * e1 + slot[0][dt][(r & 3) + 8 * rq + 4 * lg2][q] * e2) * inv;
                }
                *(f32x4*)(out + ((size_t)b * TT + qq) * DD + dt * 32 + rq * 8 + lg2 * 4) = o4;
            }
    }
}

extern "C" void kernel_launch(void* const* d_in, const int* in_sizes, int n_in,
                              void* d_out, int out_size, void* d_ws, size_t ws_size,
                              hipStream_t stream) {
    const float* x  = (const float*)d_in[0];
    const float* Wq = (const float*)d_in[1];
    const float* Wk = (const float*)d_in[2];
    const float* Wv = (const float*)d_in[3];
    float* out = (float*)d_out;

    char* ws = (char*)d_ws;
    short* Wall = (short*)ws;                              //   786,432 B
    short* Q    = (short*)(ws + 786432);                   // 4,194,304 B
    short* K    = (short*)(ws + 786432 + 4194304);
    short* Vs   = (short*)(ws + 786432 + 2 * 4194304);     // total ~13.4 MB

    prep_w<<<384, 256, 0, stream>>>(Wq, Wk, Wv, Wall);
    qkv_fused<<<dim3(256, 3), 256, 0, stream>>>(x, Wall, Q, K, Vs);
    attn32<<<BB * 64, 512, 0, stream>>>(Q, K, Vs, out);
}

// Round 29
// 67.216 us; speedup vs baseline: 1.1041x; 1.1041x over previous
//
#include <hip/hip_runtime.h>
#include <hip/hip_bf16.h>

#define TT 2048
#define CC 1024
#define DD 128
#define BB 8
#define BK 32
#define NSTEP (CC / BK)   // 32 K-steps

typedef __attribute__((ext_vector_type(8))) short bf16x8;
typedef __attribute__((ext_vector_type(4))) float f32x4;
typedef __attribute__((ext_vector_type(16))) float f32x16;
typedef __attribute__((ext_vector_type(4))) short short4v;

// Native bf16 convert (RNE) — compiles to v_cvt_pk_bf16_f32 pairs.
__device__ inline short f2bf(float f) {
    __bf16 h = (__bf16)f;
    union { __bf16 b; short s; } u; u.b = h;
    return u.s;
}

__device__ inline unsigned pack2(float lo, float hi) {  // two f32 -> packed bf16x2 word
    return (unsigned)(unsigned short)f2bf(lo) | ((unsigned)(unsigned short)f2bf(hi) << 16);
}

// async global->LDS, 16B per lane (guide §5 / Common-mistake #1)
#define GLOAD16(gp, lp) __builtin_amdgcn_global_load_lds(                       \
    (const __attribute__((address_space(1))) unsigned int*)(const void*)(gp),   \
    (__attribute__((address_space(3))) unsigned int*)(void*)(lp), 16, 0, 0)

// ---------------- Kernel 1: pack Wq|Wk|Wv -> bf16 Wall[384][1024] ----------------
__global__ __launch_bounds__(256) void prep_w(const float* __restrict__ Wq,
                                              const float* __restrict__ Wk,
                                              const float* __restrict__ Wv,
                                              short* __restrict__ Wall) {
    int row = blockIdx.x;  // 0..383
    const float* src = row < 128 ? Wq + (size_t)row * CC
                     : row < 256 ? Wk + (size_t)(row - 128) * CC
                                 : Wv + (size_t)(row - 256) * CC;
    short* dst = Wall + (size_t)row * CC;
    int j = threadIdx.x * 4;
    float4 f = *(const float4*)(src + j);
    short4v s = { f2bf(f.x), f2bf(f.y), f2bf(f.z), f2bf(f.w) };
    *(short4v*)(dst + j) = s;
}

// ---------------- Kernel 2: fused QKV GEMM (5x-verified best) ---------------------
// Tile 64(M)x128(N), BK=32, 4 waves (2x2), grid (256,3): col-tile -> Q/K/Vs.
// A staged fp32 with (row&7)<<4 XOR-swizzle (pre-swizzled global src, full-offset-
// XOR read). B staged bf16 linear, 4 lanes per row (64B coalesced segments).
__global__ __launch_bounds__(256) void qkv_fused(const float* __restrict__ X,
                                                 const short* __restrict__ Wall,
                                                 short* __restrict__ Q,
                                                 short* __restrict__ K,
                                                 short* __restrict__ Vs) {
    __shared__ char lds[2 * 16384];   // per buf: A fp32 8KB | B bf16 8KB
    int tid = threadIdx.x, lane = tid & 63, wid = tid >> 6;
    int wm = wid >> 1, wn = wid & 1;
    int lg = lane >> 4, lr = lane & 15;
    int m0 = blockIdx.x * 64;
    int n0 = blockIdx.y * 128;

    // A staging: 512 16B-chunks; thread stages chunks tid and tid+256 (rows +32)
    int rA = tid >> 3;                     // 0..31
    int cA = (tid & 7) * 16;               // byte col in 128B row
    int sA = cA ^ ((rA & 7) << 4);         // pre-swizzled source col
    const char* gA0 = (const char*)(X + (size_t)(m0 + rA) * CC) + sA;
    const char* gA1 = (const char*)(X + (size_t)(m0 + rA + 32) * CC) + sA;
    // B staging: 512 16B-chunks linear; rows n0..n0+127, 4 lanes per row (64B)
    int rB = tid >> 2, cB = (tid & 3) * 16;
    const char* gB0 = (const char*)(Wall + (size_t)(n0 + rB) * CC) + cB;
    const char* gB1 = (const char*)(Wall + (size_t)(n0 + rB + 64) * CC) + cB;

    f32x4 acc[2][4] = {};

#define STAGEF(t_, buf_) do {                                                   \
        char* b_ = lds + (buf_) * 16384;                                        \
        size_t ka_ = (size_t)(t_) * 128;   /* bytes into fp32 A row */          \
        size_t kb_ = (size_t)(t_) * 64;    /* bytes into bf16 B row */          \
        GLOAD16(gA0 + ka_, b_ + tid * 16);                                      \
        GLOAD16(gA1 + ka_, b_ + 4096 + tid * 16);                               \
        GLOAD16(gB0 + kb_, b_ + 8192 + tid * 16);                               \
        GLOAD16(gB1 + kb_, b_ + 12288 + tid * 16);                              \
    } while (0)

#define KSTEPF(buf_) do {                                                       \
        const char* b_ = lds + (buf_) * 16384;                                  \
        bf16x8 a_[2], bb_[4];                                                   \
        int swz_ = (lr & 7) << 4;                                               \
        _Pragma("unroll")                                                       \
        for (int mi = 0; mi < 2; ++mi) {                                        \
            const char* Ap_ = b_ + (wm * 32 + mi * 16 + lr) * 128;              \
            f32x4 lo_ = *(const f32x4*)(Ap_ + ((lg * 32) ^ swz_));              \
            f32x4 hi_ = *(const f32x4*)(Ap_ + ((lg * 32 + 16) ^ swz_));         \
            bf16x8 t_;                                                          \
            t_[0] = f2bf(lo_[0]); t_[1] = f2bf(lo_[1]);                         \
            t_[2] = f2bf(lo_[2]); t_[3] = f2bf(lo_[3]);                         \
            t_[4] = f2bf(hi_[0]); t_[5] = f2bf(hi_[1]);                         \
            t_[6] = f2bf(hi_[2]); t_[7] = f2bf(hi_[3]);                         \
            a_[mi] = t_;                                                        \
        }                                                                       \
        _Pragma("unroll")                                                       \
        for (int nj = 0; nj < 4; ++nj)                                          \
            bb_[nj] = *(const bf16x8*)(b_ + 8192 + (wn*64 + nj*16 + lr) * 64 + lg*16);\
        _Pragma("unroll")                                                       \
        for (int mi = 0; mi < 2; ++mi)                                          \
            _Pragma("unroll")                                                   \
            for (int nj = 0; nj < 4; ++nj)                                      \
                acc[mi][nj] = __builtin_amdgcn_mfma_f32_16x16x32_bf16(a_[mi], bb_[nj], acc[mi][nj], 0, 0, 0);\
    } while (0)

    STAGEF(0, 0);
#pragma unroll 2
    for (int t = 0; t < NSTEP; ++t) {
        __syncthreads();                   // staged tile t visible; reads of t-1 done
        if (t + 1 < NSTEP) STAGEF(t + 1, (t + 1) & 1);
        KSTEPF(t & 1);
    }
#undef STAGEF
#undef KSTEPF

    int bidx = m0 >> 11;
    int nt = blockIdx.y;
#pragma unroll
    for (int mi = 0; mi < 2; ++mi) {
        int row = m0 + wm * 32 + mi * 16 + lg * 4;
        int t = row - bidx * TT;
#pragma unroll
        for (int nj = 0; nj < 4; ++nj) {
            int col = wn * 64 + nj * 16 + lr;
            if (nt == 0) {
                short* dst = Q + ((size_t)bidx * TT + t) * DD + col;
#pragma unroll
                for (int r = 0; r < 4; ++r) dst[(size_t)r * DD] = f2bf(acc[mi][nj][r]);
            } else if (nt == 1) {
                short* dst = K + ((size_t)bidx * TT + t) * DD + col;
#pragma unroll
                for (int r = 0; r < 4; ++r) dst[(size_t)r * DD] = f2bf(acc[mi][nj][r]);
            } else {
                short4v v4;
#pragma unroll
                for (int r = 0; r < 4; ++r) v4[r] = f2bf(acc[mi][nj][r]);
                *(short4v*)(Vs + (size_t)bidx * TT * DD
                               + (size_t)(t >> 4) * 2048 + col * 16 + (t & 15)) = v4;
            }
        }
    }
}

// ---------------- PV macro: uses preloaded V fragments (r13-verified) ----------------
#define PV_CHUNK(WS, H, CB) do {                                                   \
    unsigned a0 = WS[4*(H)+0], a1 = WS[4*(H)+1];                                   \
    unsigned b0 = WS[4*(H)+2], b1 = WS[4*(H)+3];                                   \
    unsigned xa0 = (unsigned)__shfl_xor((int)a0, 32, 64);                          \
    unsigned xa1 = (unsigned)__shfl_xor((int)a1, 32, 64);                          \
    unsigned xb0 = (unsigned)__shfl_xor((int)b0, 32, 64);                          \
    unsigned xb1 = (unsigned)__shfl_xor((int)b1, 32, 64);                          \
    union { unsigned u[4]; bf16x8 v; } pu;                                         \
    pu.u[0] = lg2 ? xb0 : a0;                                                      \
    pu.u[1] = lg2 ? xb1 : a1;                                                      \
    pu.u[2] = lg2 ? b0  : xa0;                                                     \
    pu.u[3] = lg2 ? b1  : xa1;                                                     \
    _Pragma("unroll")                                                              \
    for (int dt = 0; dt < 4; ++dt)                                                 \
        acc[dt] = __builtin_amdgcn_mfma_f32_32x32x16_bf16(vf[CB][dt], pu.v, acc[dt], 0,0,0);\
} while (0)

// ---------------- Kernel 3: causal flash attention, 8 waves / q-tile (r25 best) ---
// qt map REVERTED to the 5x-verified descending order (r28's "balanced pairing"
// regressed 67.2->74.2: dispatch isn't fixed index->CU pairing, and putting light
// blocks last created a low-occupancy tail).
__global__ __launch_bounds__(512) void attn32(const short* __restrict__ Q,
                                              const short* __restrict__ K,
                                              const short* __restrict__ Vt,
                                              float* __restrict__ out) {
    __shared__ float slot[4][4][32][33];
    __shared__ float ml[4][2][32];

    int tid = threadIdx.x;
    int lane = tid & 63, w = tid >> 6;       // w = 0..7
    int q = lane & 31, lg2 = lane >> 5;
    int bid = blockIdx.x;
    int b = bid & 7;
    int qt = 63 - (bid >> 3);                // heavy q-tiles first -> backfill balance
    int r0 = qt * 32;
    int qq = r0 + q;

    const short* Qb = Q + (size_t)b * TT * DD;
    const short* Kb = K + (size_t)b * TT * DD;
    const short* Vb = Vt + (size_t)b * TT * DD;

    bf16x8 qf[8];
#pragma unroll
    for (int kc = 0; kc < 8; ++kc)
        qf[kc] = *(const bf16x8*)(Qb + (size_t)qq * DD + kc * 16 + lg2 * 8);

    f32x16 acc[4] = {};
    float mb = -INFINITY, l = 0.f;
    const float scale = 0.08838834764831845f;
    int kend = r0 + 32;

    for (int kt = w; kt * 64 < kend; kt += 8) {
        int kbase = kt * 64;
        f32x16 s0 = {}, s1 = {};
        const short* Kp0 = Kb + (size_t)(kbase + q) * DD + lg2 * 8;
        const short* Kp1 = Kp0 + (size_t)32 * DD;
#pragma unroll
        for (int kc = 0; kc < 8; ++kc) {
            bf16x8 k0 = *(const bf16x8*)(Kp0 + kc * 16);
            bf16x8 k1 = *(const bf16x8*)(Kp1 + kc * 16);
            s0 = __builtin_amdgcn_mfma_f32_32x32x16_bf16(k0, qf[kc], s0, 0, 0, 0);
            s1 = __builtin_amdgcn_mfma_f32_32x32x16_bf16(k1, qf[kc], s1, 0, 0, 0);
        }

        // V preload: addresses independent of softmax -> latency hides under it
        bf16x8 vf[4][4];
#pragma unroll
        for (int cb = 0; cb < 4; ++cb) {
            const short* Vp = Vb + ((size_t)((kbase >> 4) + cb) * 128 + q) * 16 + lg2 * 8;
#pragma unroll
            for (int dt = 0; dt < 4; ++dt)
                vf[cb][dt] = *(const bf16x8*)(Vp + dt * 512);
        }

        if (kbase + 63 > r0) {
#pragma unroll
            for (int r = 0; r < 16; ++r) {
                int kl = (r & 3) + 8 * (r >> 2) + 4 * lg2;
                s0[r] = (kbase + kl > qq) ? -INFINITY : s0[r] * scale;
                s1[r] = (kbase + 32 + kl > qq) ? -INFINITY : s1[r] * scale;
            }
        } else {
#pragma unroll
            for (int r = 0; r < 16; ++r) { s0[r] *= scale; s1[r] *= scale; }
        }

        float tmx[16];
#pragma unroll
        for (int r = 0; r < 16; ++r) tmx[r] = fmaxf(s0[r], s1[r]);
#pragma unroll
        for (int st = 8; st; st >>= 1)
#pragma unroll
            for (int r = 0; r < 8; ++r) if (r < st) tmx[r] = fmaxf(tmx[r], tmx[r + st]);
        float pm = fmaxf(tmx[0], __shfl_xor(tmx[0], 32, 64));

        if (__any(pm > mb + 8.f)) {
            float mn = fmaxf(mb, pm);
            float mc = (mn == -INFINITY) ? 0.f : mn;
            float sc = __expf(mb - mc);
            mb = mc; l *= sc;
#pragma unroll
            for (int dt = 0; dt < 4; ++dt)
#pragma unroll
                for (int r = 0; r < 16; ++r) acc[dt][r] *= sc;
        }

#pragma unroll
        for (int r = 0; r < 16; ++r) { s0[r] = __expf(s0[r] - mb); s1[r] = __expf(s1[r] - mb); }

        float ts[16];
#pragma unroll
        for (int r = 0; r < 16; ++r) ts[r] = s0[r] + s1[r];
#pragma unroll
        for (int st = 8; st; st >>= 1)
#pragma unroll
            for (int r = 0; r < 8; ++r) if (r < st) ts[r] += ts[r + st];
        l += ts[0] + __shfl_xor(ts[0], 32, 64);

        unsigned w0[8], w1[8];
#pragma unroll
        for (int k2 = 0; k2 < 8; ++k2) {
            w0[k2] = pack2(s0[2 * k2], s0[2 * k2 + 1]);
            w1[k2] = pack2(s1[2 * k2], s1[2 * k2 + 1]);
        }

        PV_CHUNK(w0, 0, 0);
        PV_CHUNK(w0, 1, 1);
        PV_CHUNK(w1, 0, 2);
        PV_CHUNK(w1, 1, 3);
    }

    // ---- level 1: waves 4-7 fold into waves 0-3 ----
    if (w >= 4) {
        int s = w - 4;
#pragma unroll
        for (int dt = 0; dt < 4; ++dt)
#pragma unroll
            for (int r = 0; r < 16; ++r)
                slot[s][dt][(r & 3) + 8 * (r >> 2) + 4 * lg2][q] = acc[dt][r];
        if (lg2 == 0) { ml[s][0][q] = mb; ml[s][1][q] = l; }
    }
    __syncthreads();
    if (w < 4) {
        int s = w;
        float m2 = ml[s][0][q], l2 = ml[s][1][q];
        float M = fmaxf(mb, m2);
        float Mc = (M == -INFINITY) ? 0.f : M;
        float e1 = __expf(mb - Mc), e2 = __expf(m2 - Mc);
        mb = Mc; l = l * e1 + l2 * e2;
#pragma unroll
        for (int dt = 0; dt < 4; ++dt)
#pragma unroll
            for (int r = 0; r < 16; ++r)
                acc[dt][r] = acc[dt][r] * e1 + slot[s][dt][(r & 3) + 8 * (r >> 2) + 4 * lg2][q] * e2;
    }
    __syncthreads();
    // ---- level 2: waves 2-3 fold into 0-1 ----
    if (w >= 2 && w < 4) {
        int s = w - 2;
#pragma unroll
        for (int dt = 0; dt < 4; ++dt)
#pragma unroll
            for (int r = 0; r < 16; ++r)
                slot[s][dt][(r & 3) + 8 * (r >> 2) + 4 * lg2][q] = acc[dt][r];
        if (lg2 == 0) { ml[s][0][q] = mb; ml[s][1][q] = l; }
    }
    __syncthreads();
    if (w < 2) {
        int s = w;
        float m2 = ml[s][0][q], l2 = ml[s][1][q];
        float M = fmaxf(mb, m2);
        float Mc = (M == -INFINITY) ? 0.f : M;
        float e1 = __expf(mb - Mc), e2 = __expf(m2 - Mc);
        mb = Mc; l = l * e1 + l2 * e2;
#pragma unroll
        for (int dt = 0; dt < 4; ++dt)
#pragma unroll
            for (int r = 0; r < 16; ++r)
                acc[dt][r] = acc[dt][r] * e1 + slot[s][dt][(r & 3) + 8 * (r >> 2) + 4 * lg2][q] * e2;
    }
    __syncthreads();
    if (w == 1) {
#pragma unroll
        for (int dt = 0; dt < 4; ++dt)
#pragma unroll
            for (int r = 0; r < 16; ++r)
                slot[0][dt][(r & 3) + 8 * (r >> 2) + 4 * lg2][q] = acc[dt][r];
        if (lg2 == 0) { ml[0][0][q] = mb; ml[0][1][q] = l; }
    }
    __syncthreads();
    if (w == 0) {
        float m2 = ml[0][0][q], l2 = ml[0][1][q];
        float M = fmaxf(mb, m2);
        float Mc = (M == -INFINITY) ? 0.f : M;
        float e1 = __expf(mb - Mc), e2 = __expf(m2 - Mc);
        l = l * e1 + l2 * e2;
        float inv = 1.f / l;
#pragma unroll
        for (int dt = 0; dt < 4; ++dt)
#pragma unroll
            for (int rq = 0; rq < 4; ++rq) {
                f32x4 o4;
#pragma unroll
                for (int j = 0; j < 4; ++j) {
                    int r = rq * 4 + j;
                    o4[j] = (acc[dt][r] * e1 + slot[0][dt][(r & 3) + 8 * rq + 4 * lg2][q] * e2) * inv;
                }
                *(f32x4*)(out + ((size_t)b * TT + qq) * DD + dt * 32 + rq * 8 + lg2 * 4) = o4;
            }
    }
}

extern "C" void kernel_launch(void* const* d_in, const int* in_sizes, int n_in,
                              void* d_out, int out_size, void* d_ws, size_t ws_size,
                              hipStream_t stream) {
    const float* x  = (const float*)d_in[0];
    const float* Wq = (const float*)d_in[1];
    const float* Wk = (const float*)d_in[2];
    const float* Wv = (const float*)d_in[3];
    float* out = (float*)d_out;

    char* ws = (char*)d_ws;
    short* Wall = (short*)ws;                              //   786,432 B
    short* Q    = (short*)(ws + 786432);                   // 4,194,304 B
    short* K    = (short*)(ws + 786432 + 4194304);
    short* Vs   = (short*)(ws + 786432 + 2 * 4194304);     // total ~13.4 MB

    prep_w<<<384, 256, 0, stream>>>(Wq, Wk, Wv, Wall);
    qkv_fused<<<dim3(256, 3), 256, 0, stream>>>(x, Wall, Q, K, Vs);
    attn32<<<BB * 64, 512, 0, stream>>>(Q, K, Vs, out);
}